// Round 1
// baseline (377.806 us; speedup 1.0000x reference)
//
#include <hip/hip_runtime.h>
#include <cstdint>
#include <cmath>

typedef _Float16 f16;
typedef _Float16 f16x8 __attribute__((ext_vector_type(8)));
typedef float f32x4 __attribute__((ext_vector_type(4)));

// async 16B/lane global->LDS (lds dst = wave-uniform base + lane*16)
__device__ inline void gld_lds16(const void* g, void* l) {
  __builtin_amdgcn_global_load_lds(
      (__attribute__((address_space(1))) void*)(uintptr_t)g,
      (__attribute__((address_space(3))) void*)l, 16, 0, 0);
}

// ---------------------------------------------------------------------------
// Build X1 = [enc_flat(10240) | word(512) | persona[speaker](512) | h0(512)] in fp16
// grid (23, 256) x 256 threads; each thread packs 2 halves (one dword store).
__global__ __launch_bounds__(256) void build_x1_kernel(
    const float* __restrict__ enc, const float* __restrict__ word,
    const float* __restrict__ pers, const int* __restrict__ speaker,
    const float* __restrict__ h0, f16* __restrict__ X)
{
  const int b  = blockIdx.y;
  const int k2 = blockIdx.x * 256 + threadIdx.x;   // 0..5887
  const int k  = k2 * 2;
  float v0, v1;
  if (k < 10240) {
    const float* p = enc + (long long)b * 10240 + k; v0 = p[0]; v1 = p[1];
  } else if (k < 10752) {
    const float* p = word + b * 512 + (k - 10240);   v0 = p[0]; v1 = p[1];
  } else if (k < 11264) {
    const float* p = pers + (long long)speaker[b] * 512 + (k - 10752); v0 = p[0]; v1 = p[1];
  } else {
    const float* p = h0 + b * 512 + (k - 11264);     v0 = p[0]; v1 = p[1];
  }
  union { f16 h[2]; unsigned int u; } pk;
  pk.h[0] = (f16)v0; pk.h[1] = (f16)v1;
  ((unsigned int*)X)[(long long)b * 5888 + k2] = pk.u;
}

// ---------------------------------------------------------------------------
// fp16-input MFMA GEMM: C[m][n] = sum_k A16[m][k&akmask..] * f16(B(k,n))
// A: fp16, global_load_lds staged. B: fp32 (two K-ranges B0 / B1 at ksw),
// converted to fp16 at staging. BM=BN=128, BK=32, 256 thr (4 waves 2x2),
// per-wave 64x64 = 4x4 16x16x32 frags. blockIdx.z = split-K index, writes
// partials at C + z*c_split_stride (plain stores, no atomics).
__global__ __launch_bounds__(256, 2) void gemm_f16_kernel(
    const f16* __restrict__ A, int lda, int a_kmask,
    const float* __restrict__ B0, const float* __restrict__ B1, int ksw, int ldb,
    float* __restrict__ C, int ldc, long long c_split_stride, int kchunk)
{
  // A: rows of 32 halves (64B), chunk-swizzled: elem(m, k=8c+r) at
  //    m*32 + 8*(c ^ ((m>>1)&3)) + r  -> conflict-free b128 reads, no pad
  // B: [n][k] rows of 40 halves (pad), elem at n*40 + 8*((k>>3)^((n>>4)&3)) + (k&7)
  __shared__ __align__(16) f16 Ah[128 * 32];
  __shared__ __align__(16) f16 Bh[128 * 40];

  const int tid  = threadIdx.x;
  const int lane = tid & 63;
  const int wave = tid >> 6;
  const int m0 = blockIdx.x * 128;
  const int n0 = blockIdx.y * 128;
  const int kbeg = blockIdx.z * kchunk;
  const int kend = kbeg + kchunk;
  float* Cs = C + (long long)blockIdx.z * c_split_stride;

  const int wm = (wave & 1) * 64;
  const int wn = (wave >> 1) * 64;

  f32x4 acc[4][4] = {};

  // A staging lane mapping: lane i -> row (i>>2), stored-chunk (i&3),
  // actual k-chunk = (i&3) ^ ((i>>3)&3)  (matches f(m)=(m>>1)&3, rb mult 16)
  const int a_row16 = lane >> 2;
  const int a_ksub  = (((lane & 3) ^ ((lane >> 3) & 3))) * 8;

  // B staging: thread -> k-row (tid>>3, 0..31), 16 n at (tid&7)*16
  const int bk  = tid >> 3;
  const int bkc = bk >> 3;
  const int bkr = bk & 7;
  const int bn_base = (tid & 7) * 16;

  for (int kt = kbeg; kt < kend; kt += 32) {
    const int akb = kt & a_kmask;
    #pragma unroll
    for (int half = 0; half < 2; half++) {
      const int rb = wave * 32 + half * 16;
      const f16* gp = A + (long long)(m0 + rb + a_row16) * lda + akb + a_ksub;
      gld_lds16((const void*)gp, (void*)&Ah[rb * 32]);
    }
    {
      const int krow = kt + bk;
      const float* bp = (krow >= ksw) ? (B1 + (long long)(krow - ksw) * ldb)
                                      : (B0 + (long long)krow * ldb);
      bp += n0 + bn_base;
      #pragma unroll
      for (int j = 0; j < 4; j++) {
        const float4 v = *(const float4*)(bp + j * 4);
        const float vv[4] = {v.x, v.y, v.z, v.w};
        #pragma unroll
        for (int e = 0; e < 4; e++) {
          const int n = bn_base + j * 4 + e;
          Bh[n * 40 + ((bkc ^ ((n >> 4) & 3)) * 8) + bkr] = (f16)vv[e];
        }
      }
    }
    __syncthreads();

    f16x8 af[4], bf[4];
    #pragma unroll
    for (int mi = 0; mi < 4; mi++) {
      const int m = wm + mi * 16 + (lane & 15);
      const int c = (lane >> 4) ^ ((m >> 1) & 3);
      af[mi] = *(const f16x8*)&Ah[m * 32 + c * 8];
    }
    #pragma unroll
    for (int ni = 0; ni < 4; ni++) {
      const int n = wn + ni * 16 + (lane & 15);
      const int c = (lane >> 4) ^ ((n >> 4) & 3);
      bf[ni] = *(const f16x8*)&Bh[n * 40 + c * 8];
    }
    #pragma unroll
    for (int mi = 0; mi < 4; mi++)
      #pragma unroll
      for (int ni = 0; ni < 4; ni++)
        acc[mi][ni] = __builtin_amdgcn_mfma_f32_16x16x32_f16(af[mi], bf[ni], acc[mi][ni], 0, 0, 0);
    __syncthreads();
  }

  // C/D layout: col = lane&15, row = (lane>>4)*4 + r
  #pragma unroll
  for (int mi = 0; mi < 4; mi++) {
    const int r0 = m0 + wm + mi * 16 + (lane >> 4) * 4;
    #pragma unroll
    for (int ni = 0; ni < 4; ni++) {
      const int cc = n0 + wn + ni * 16 + (lane & 15);
      #pragma unroll
      for (int r = 0; r < 4; r++)
        Cs[(long long)(r0 + r) * ldc + cc] = acc[mi][ni][r];
    }
  }
}

// ---------------------------------------------------------------------------
// Reduce split-K partials + bias, apply LSTM gates (i,f,g,o; relu cell act).
__global__ __launch_bounds__(256) void gate_kernel(
    const float* __restrict__ zbase, int nsplit, const float* __restrict__ bias,
    const float* __restrict__ c_prev, float* __restrict__ c_out,
    f16* __restrict__ h16_out, float* __restrict__ h32_out)
{
  const int idx = blockIdx.x * 256 + threadIdx.x;   // 0..131071
  const int j = idx & 511;
  const int b = idx >> 9;
  const long long zo = (long long)b * 2048 + j;
  float zi = bias[j], zf = bias[j + 512], zg = bias[j + 1024], zo4 = bias[j + 1536];
  for (int s = 0; s < nsplit; s++) {
    const float* z = zbase + (long long)s * 524288;
    zi += z[zo]; zf += z[zo + 512]; zg += z[zo + 1024]; zo4 += z[zo + 1536];
  }
  const float gi = 1.f / (1.f + expf(-zi));
  const float gf = 1.f / (1.f + expf(-zf));
  const float gg = fmaxf(zg, 0.f);
  const float go = 1.f / (1.f + expf(-zo4));
  const float cn = gf * c_prev[idx] + gi * gg;
  const float hn = go * fmaxf(cn, 0.f);
  c_out[idx] = cn;
  h16_out[idx] = (f16)hn;
  if (h32_out) h32_out[idx] = hn;
}

// ---------------------------------------------------------------------------
// In-place softmax over V=32000 per row; one block (1024 thr) per row,
// row held in registers (32/thread), + bd bias.
__global__ __launch_bounds__(1024) void softmax_kernel(
    float* __restrict__ logits, const float* __restrict__ bd)
{
  const int row = blockIdx.x;
  const int t = threadIdx.x;
  float* rp = logits + (long long)row * 32000;
  float l[32];
  float m = -1e30f;
  #pragma unroll
  for (int i = 0; i < 32; i++) {
    const int v = t + i * 1024;
    if (v < 32000) { l[i] = rp[v] + bd[v]; m = fmaxf(m, l[i]); }
    else l[i] = -1e30f;
  }
  #pragma unroll
  for (int off = 32; off > 0; off >>= 1) m = fmaxf(m, __shfl_xor(m, off, 64));
  __shared__ float redm[16];
  __shared__ float reds[16];
  const int w = t >> 6;
  if ((t & 63) == 0) redm[w] = m;
  __syncthreads();
  float bm = redm[0];
  #pragma unroll
  for (int i = 1; i < 16; i++) bm = fmaxf(bm, redm[i]);
  float s = 0.f;
  #pragma unroll
  for (int i = 0; i < 32; i++) {
    const float e = expf(l[i] - bm);
    l[i] = e;
    s += e;          // OOB lanes: exp(-huge) == 0
  }
  #pragma unroll
  for (int off = 32; off > 0; off >>= 1) s += __shfl_xor(s, off, 64);
  if ((t & 63) == 0) reds[w] = s;
  __syncthreads();
  float ts = 0.f;
  #pragma unroll
  for (int i = 0; i < 16; i++) ts += reds[i];
  const float inv = 1.0f / ts;
  #pragma unroll
  for (int i = 0; i < 32; i++) {
    const int v = t + i * 1024;
    if (v < 32000) rp[v] = l[i] * inv;
  }
}

// ---------------------------------------------------------------------------
extern "C" void kernel_launch(void* const* d_in, const int* in_sizes, int n_in,
                              void* d_out, int out_size, void* d_ws, size_t ws_size,
                              hipStream_t stream) {
  const float* enc     = (const float*)d_in[0];
  const float* word    = (const float*)d_in[1];
  const float* h0      = (const float*)d_in[2];
  const float* c0      = (const float*)d_in[3];
  const int*   speaker = (const int*)d_in[4];
  // d_in[5] addressee unused (is_speaker branch)
  const float* pers = (const float*)d_in[6];
  const float* W1 = (const float*)d_in[7];
  const float* U1 = (const float*)d_in[8];
  const float* b1 = (const float*)d_in[9];
  const float* W2 = (const float*)d_in[10];
  const float* U2 = (const float*)d_in[11];
  const float* b2 = (const float*)d_in[12];
  const float* W3 = (const float*)d_in[13];
  const float* U3 = (const float*)d_in[14];
  const float* b3 = (const float*)d_in[15];
  const float* W4 = (const float*)d_in[16];
  const float* U4 = (const float*)d_in[17];
  const float* b4 = (const float*)d_in[18];
  const float* Wd = (const float*)d_in[19];
  const float* bd = (const float*)d_in[20];

  float* out = (float*)d_out;
  // d_out probs region (32.77 MB) doubles as scratch before the decoder runs:
  //   [0, 16 MB)        : split-K z partials (8 x 524288 floats)
  //   [16 MB, 22.8 MB)  : X1 fp16 (256 x 11776)
  float* zpart = out;
  f16*   X1h   = (f16*)((char*)d_out + 16777216);
  float* h4_out = out + 8192000;
  float* c4_out = out + 8192000 + 131072;

  float* ws_c   = (float*)d_ws;                       // 512 KB
  f16*   ws_h16 = (f16*)((char*)d_ws + 524288);       // 256 KB

  const int BIG = 1 << 29;

  build_x1_kernel<<<dim3(23, 256), 256, 0, stream>>>(enc, word, pers, speaker, h0, X1h);

  // layer 1: K = 11264 (W1) + 512 (U1), split-K 8 (256 blocks)
  gemm_f16_kernel<<<dim3(2, 16, 8), 256, 0, stream>>>(
      X1h, 11776, 0x7fffffff, W1, U1, 11264, 2048, zpart, 2048, 524288LL, 1472);
  gate_kernel<<<dim3(512), 256, 0, stream>>>(zpart, 8, b1, c0, ws_c, ws_h16, nullptr);

  // layer 2: K = 1024 (h wraps at 512), split-K 4
  gemm_f16_kernel<<<dim3(2, 16, 4), 256, 0, stream>>>(
      ws_h16, 512, 511, W2, U2, 512, 2048, zpart, 2048, 524288LL, 256);
  gate_kernel<<<dim3(512), 256, 0, stream>>>(zpart, 4, b2, ws_c, ws_c, ws_h16, nullptr);

  // layer 3
  gemm_f16_kernel<<<dim3(2, 16, 4), 256, 0, stream>>>(
      ws_h16, 512, 511, W3, U3, 512, 2048, zpart, 2048, 524288LL, 256);
  gate_kernel<<<dim3(512), 256, 0, stream>>>(zpart, 4, b3, ws_c, ws_c, ws_h16, nullptr);

  // layer 4: also emit h4/c4 fp32 into d_out
  gemm_f16_kernel<<<dim3(2, 16, 4), 256, 0, stream>>>(
      ws_h16, 512, 511, W4, U4, 512, 2048, zpart, 2048, 524288LL, 256);
  gate_kernel<<<dim3(512), 256, 0, stream>>>(zpart, 4, b4, ws_c, c4_out, ws_h16, h4_out);

  // decoder: logits = h4 @ Wd, in place in probs region (500 blocks)
  gemm_f16_kernel<<<dim3(2, 250, 1), 256, 0, stream>>>(
      ws_h16, 512, 0x7fffffff, Wd, Wd, BIG, 32000, out, 32000, 0LL, 512);

  softmax_kernel<<<dim3(256), 1024, 0, stream>>>(out, bd);
}